// Round 7
// baseline (116.004 us; speedup 1.0000x reference)
//
#include <hip/hip_runtime.h>

#define NROWS 8192
#define DDIM  64
#define KNN   32
#define MAXIT 100

// alpha/beta arrive as 1-element arrays; robust to int32 or float32 encoding.
__device__ __forceinline__ float scalar_val(const void* p) {
    int iv = *(const int*)p;
    if (iv > -1000000 && iv < 1000000) return (float)iv;
    return *(const float*)p;
}

// Role-specialized single dispatch, 2048 blocks:
//   even blockIdx  -> ZERO block for rows 8m..8m+7: bitmap from idx, then a
//                     pure store stream (zeros for every non-hit dword).
//   odd  blockIdx  -> COMPUTE block for the same rows: distances, Newton,
//                     dedupe, embs, Ypass, and ONLY the live scatter dwords.
// Each dword of A is written by exactly one agent -> no sync/order needed.
__global__ __launch_bounds__(256, 4) void school_fused_kernel(
    const float* __restrict__ Y,
    const float* __restrict__ semH,
    const float* __restrict__ orthoH,
    const int*   __restrict__ idx,
    const void*  alpha_p,
    const void*  beta_p,
    float* __restrict__ embs,   // N*D
    float* __restrict__ A,      // N*N
    float* __restrict__ Yout)   // N*D
{
    const int tid  = threadIdx.x;
    const int j    = tid & 31;      // lane within half-wave = neighbor slot
    const int r    = tid >> 5;      // row-within-block, 0..7 (half-wave id)
    const int m    = blockIdx.x >> 1;
    const int row0 = m * 8;
    const int row  = row0 + r;

    if ((blockIdx.x & 1) == 0) {
        // ================= ZERO BLOCK =================
        __shared__ unsigned bmp[8][64];          // per-row 2048-bit dword-hit bitmap
        ((unsigned*)bmp)[tid]       = 0u;
        ((unsigned*)bmp)[tid + 256] = 0u;
        const int c = idx[row * 64 + 1 + j];     // only load; completes pre-stores
        __syncthreads();
        atomicOr(&bmp[r][c >> 5], 1u << (c & 31));
        __syncthreads();

        const float4 z4 = make_float4(0.f, 0.f, 0.f, 0.f);
        for (int rr = 0; rr < 8; ++rr) {
            float4* R4 = (float4*)(A + (size_t)(row0 + rr) * NROWS);
            float*  Rf = A + (size_t)(row0 + rr) * NROWS;
            #pragma unroll
            for (int k = 0; k < 8; ++k) {
                const int i = tid + (k << 8);                    // float4 idx 0..2047
                const unsigned nib = (bmp[rr][i >> 3] >> ((i & 7) << 2)) & 0xFu;
                if (nib == 0u) {
                    R4[i] = z4;                                  // fast path (typical)
                } else {                                         // ~32 chunks/row
                    if (!(nib & 1u)) Rf[4 * i + 0] = 0.f;
                    if (!(nib & 2u)) Rf[4 * i + 1] = 0.f;
                    if (!(nib & 4u)) Rf[4 * i + 2] = 0.f;
                    if (!(nib & 8u)) Rf[4 * i + 3] = 0.f;
                }
            }
        }
        return;
    }

    // ================= COMPUTE BLOCK =================
    __shared__ int   col_s[8][KNN];
    __shared__ float w_s[8][KNN];
    __shared__ float ad_s[8][KNN];

    const float alpha = scalar_val(alpha_p);
    const float beta  = scalar_val(beta_p);

    // ---- Phase 0: neighbor ids -> LDS ----
    const int col = idx[row * 64 + 1 + j];       // idxa0 = idx[:, 1:33]
    col_s[r][j] = col;

    // ---- Phase 1: distances, cooperative-coalesced (2 cols / 16-lane group)
    const float4* Y4 = (const float4*)Y;
    const float4* O4 = (const float4*)orthoH;
    const int q = j & 15;
    const float4 ownY = Y4[(size_t)row * 16 + q];
    const float4 ownO = O4[(size_t)row * 16 + q];

    #pragma unroll 4
    for (int t = 0; t < 16; ++t) {
        const int c = col_s[r][2 * t + (j >> 4)];
        const float4 gY = Y4[(size_t)c * 16 + q];
        const float4 gO = O4[(size_t)c * 16 + q];
        float ex = ownY.x - gY.x, ey = ownY.y - gY.y,
              ez = ownY.z - gY.z, ew = ownY.w - gY.w;
        float dY = ex * ex + ey * ey + ez * ez + ew * ew;
        ex = ownO.x - gO.x; ey = ownO.y - gO.y;
        ez = ownO.z - gO.z; ew = ownO.w - gO.w;
        float dO = ex * ex + ey * ey + ez * ez + ew * ew;
        #pragma unroll
        for (int mm = 1; mm <= 8; mm <<= 1) {
            dY += __shfl_xor(dY, mm, 64);
            dO += __shfl_xor(dO, mm, 64);
        }
        if ((j & 15) == 0) {
            float dfv = sqrtf(dY + 1e-8f);
            float dxv = sqrtf(dO + 1e-8f);
            ad_s[r][2 * t + (j >> 4)] = -(dxv + beta * dfv) / (2.f * alpha);
        }
    }
    const float ad = ad_s[r][j];

    // ---- Phase 2: simplex projection (32 lanes = one row) ----
    float s = ad;
    #pragma unroll
    for (int mm = 1; mm <= 16; mm <<= 1) s += __shfl_xor(s, mm, 64);
    const float v0 = ad - s * (1.f / 32.f) + (1.f / 32.f);

    float lam = 0.f;
    #pragma unroll 1
    for (int it = 0; it < MAXIT; ++it) {
        float v1 = v0 - lam;
        float p = v1 > 0.f ? v1 : 0.f;
        float c = v1 > 0.f ? 1.f : 0.f;
        #pragma unroll
        for (int mm = 1; mm <= 16; mm <<= 1) {
            p += __shfl_xor(p, mm, 64);
            c += __shfl_xor(c, mm, 64);
        }
        float step = (p - 1.f) / fmaxf(c, 1.f);
        lam += step;
        if (__all(fabsf(step) <= 1e-6f ? 1 : 0)) break;
    }
    const float w = fmaxf(v0 - lam, 0.f);

    // ---- Phase 3: dedupe (np fancy-assignment: last j wins) ----
    bool dead = false;
    for (int jj = j + 1; jj < 32; ++jj)
        dead |= (col_s[r][jj] == col);
    w_s[r][j] = dead ? 0.f : w;

    // ---- Phase 4: embs_hom[row] = sum_j w_j * semH[col_j]  (coalesced) ----
    {
        float2 acc = make_float2(0.f, 0.f);
        const float2* H2 = (const float2*)semH;
        #pragma unroll 4
        for (int jj = 0; jj < KNN; ++jj) {
            float wv = w_s[r][jj];
            int   c  = col_s[r][jj];
            float2 h = H2[(size_t)c * 32 + j];
            acc.x += wv * h.x;
            acc.y += wv * h.y;
        }
        ((float2*)embs)[(size_t)row * 32 + j] = acc;
    }

    // ---- Phase 5: Y passthrough ----
    {
        const float2* Y2 = (const float2*)(Y + (size_t)row0 * DDIM);
        float2* O2 = (float2*)(Yout + (size_t)row0 * DDIM);
        O2[tid] = Y2[tid];
    }

    // ---- Phase 6: live scatter dwords (each written exactly once fleet-wide)
    if (!dead) A[(size_t)row * NROWS + col] = w;
}

extern "C" void kernel_launch(void* const* d_in, const int* in_sizes, int n_in,
                              void* d_out, int out_size, void* d_ws, size_t ws_size,
                              hipStream_t stream) {
    const float* Y      = (const float*)d_in[0];
    const float* semH   = (const float*)d_in[1];
    const float* orthoH = (const float*)d_in[2];
    const int*   idx    = (const int*)d_in[3];
    const void*  alpha  = d_in[4];
    const void*  beta   = d_in[5];

    float* out  = (float*)d_out;
    float* embs = out;                                   // N*D
    float* A    = out + (size_t)NROWS * DDIM;            // N*N
    float* Yout = A + (size_t)NROWS * NROWS;             // N*D

    school_fused_kernel<<<2 * (NROWS / 8), 256, 0, stream>>>(
        Y, semH, orthoH, idx, alpha, beta, embs, A, Yout);
}

// Round 8
// 69.254 us; speedup vs baseline: 1.6751x; 1.6751x over previous
//
#include <hip/hip_runtime.h>

#define NROWS 8192
#define DDIM  64
#define KNN   32
#define MAXIT 100

// alpha/beta arrive as 1-element arrays; robust to int32 or float32 encoding.
__device__ __forceinline__ float scalar_val(const void* p) {
    int iv = *(const int*)p;
    if (iv > -1000000 && iv < 1000000) return (float)iv;
    return *(const float*)p;
}

// One block = 8 rows, half-wave (32 lanes) per row.
// Program order engineered around in-order vmcnt:
//   loads (idx, Y/orthoH gathers) -> consume -> ZERO-STREAM stores (non-hit
//   chunks) -> Newton/dedupe/merge-scan (pure VALU/LDS, hides under store
//   drain) -> hit-chunk stores -> overflow -> embs (tail) -> Ypass.
__global__ __launch_bounds__(256, 4) void school_fused_kernel(
    const float* __restrict__ Y,
    const float* __restrict__ semH,
    const float* __restrict__ orthoH,
    const int*   __restrict__ idx,
    const void*  alpha_p,
    const void*  beta_p,
    float* __restrict__ embs,   // N*D
    float* __restrict__ A,      // N*N
    float* __restrict__ Yout)   // N*D
{
    __shared__ int   col_s[8][KNN];
    __shared__ float w_s[8][KNN];
    __shared__ float ad_s[8][KNN];

    const int tid  = threadIdx.x;
    const int j    = tid & 31;      // lane within half-wave = neighbor slot
    const int r    = tid >> 5;      // row-within-block, 0..7 (half-wave id)
    const int row0 = blockIdx.x * 8;
    const int row  = row0 + r;

    const float alpha = scalar_val(alpha_p);
    const float beta  = scalar_val(beta_p);

    // ---- Phase 0: neighbor ids -> LDS ----
    const int col = idx[row * 64 + 1 + j];       // idxa0 = idx[:, 1:33]
    col_s[r][j] = col;

    // ---- Phase 0b: hit-mask for my chunks (positions only, no distances) ----
    // Lane j owns float4 chunks i = 32*ss + j; col c -> chunk c>>2, owner
    // (c>>2)&31, ss = c>>7. Duplicate cols map to the same bit (idempotent).
    unsigned long long hitmask = 0ull;
    #pragma unroll 1
    for (int jj = 0; jj < 32; ++jj) {
        int c = col_s[r][jj];
        if (((c >> 2) & 31) == j) hitmask |= 1ull << (c >> 7);
    }

    // ---- Phase 1: distances, cooperative-coalesced (2 cols / 16-lane group)
    const float4* Y4 = (const float4*)Y;
    const float4* O4 = (const float4*)orthoH;
    const int q = j & 15;
    const float4 ownY = Y4[(size_t)row * 16 + q];
    const float4 ownO = O4[(size_t)row * 16 + q];

    #pragma unroll 4
    for (int t = 0; t < 16; ++t) {
        const int c = col_s[r][2 * t + (j >> 4)];
        const float4 gY = Y4[(size_t)c * 16 + q];
        const float4 gO = O4[(size_t)c * 16 + q];
        float ex = ownY.x - gY.x, ey = ownY.y - gY.y,
              ez = ownY.z - gY.z, ew = ownY.w - gY.w;
        float dY = ex * ex + ey * ey + ez * ez + ew * ew;
        ex = ownO.x - gO.x; ey = ownO.y - gO.y;
        ez = ownO.z - gO.z; ew = ownO.w - gO.w;
        float dO = ex * ex + ey * ey + ez * ez + ew * ew;
        #pragma unroll
        for (int mm = 1; mm <= 8; mm <<= 1) {
            dY += __shfl_xor(dY, mm, 64);
            dO += __shfl_xor(dO, mm, 64);
        }
        if ((j & 15) == 0) {
            float dfv = sqrtf(dY + 1e-8f);
            float dxv = sqrtf(dO + 1e-8f);
            ad_s[r][2 * t + (j >> 4)] = -(dxv + beta * dfv) / (2.f * alpha);
        }
    }
    const float ad = ad_s[r][j];

    __builtin_amdgcn_sched_barrier(0);   // all gather-consumes stay above

    // ---- Phase 2: ZERO-STREAM for non-hit chunks (pure stores, ~63/lane).
    // Issued BEFORE Newton so the HBM drain overlaps the VALU tail.
    {
        const float4 z4 = make_float4(0.f, 0.f, 0.f, 0.f);
        float4* Arow4 = (float4*)(A + (size_t)row * NROWS);
        #pragma unroll 8
        for (int ss = 0; ss < 64; ++ss) {
            if (!((hitmask >> ss) & 1ull))
                Arow4[(ss << 5) + j] = z4;
        }
    }

    __builtin_amdgcn_sched_barrier(0);   // keep stores above the VALU phase

    // ---- Phase 3: simplex projection (32 lanes = one row); VALU/DS only ----
    float s = ad;
    #pragma unroll
    for (int mm = 1; mm <= 16; mm <<= 1) s += __shfl_xor(s, mm, 64);
    const float v0 = ad - s * (1.f / 32.f) + (1.f / 32.f);

    float lam = 0.f;
    #pragma unroll 1
    for (int it = 0; it < MAXIT; ++it) {
        float v1 = v0 - lam;
        float p = v1 > 0.f ? v1 : 0.f;
        float c = v1 > 0.f ? 1.f : 0.f;
        #pragma unroll
        for (int mm = 1; mm <= 16; mm <<= 1) {
            p += __shfl_xor(p, mm, 64);
            c += __shfl_xor(c, mm, 64);
        }
        float step = (p - 1.f) / fmaxf(c, 1.f);
        lam += step;
        if (__all(fabsf(step) <= 1e-6f ? 1 : 0)) break;
    }
    const float w = fmaxf(v0 - lam, 0.f);

    // ---- Phase 4: dedupe (np fancy-assignment: last j wins) ----
    bool dead = false;
    for (int jj = j + 1; jj < 32; ++jj)
        dead |= (col_s[r][jj] == col);
    w_s[r][j] = dead ? 0.f : w;

    // ---- Phase 5: k-slot scan (ascending jj => ascending apply = last-wins)
    unsigned k0 = 0xFFFFFFFFu, k1 = 0xFFFFFFFFu, k2 = 0xFFFFFFFFu, k3 = 0xFFFFFFFFu;
    float f0 = 0.f, f1 = 0.f, f2 = 0.f, f3 = 0.f;
    int nhit = 0;
    #pragma unroll 1
    for (int jj = 0; jj < 32; ++jj) {
        int c = col_s[r][jj];
        if (((c >> 2) & 31) == j) {
            unsigned key = ((unsigned)(c >> 7) << 2) | (unsigned)(c & 3);
            float wv = w_s[r][jj];
            k3 = (nhit == 3) ? key : k3;  f3 = (nhit == 3) ? wv : f3;
            k2 = (nhit == 2) ? key : k2;  f2 = (nhit == 2) ? wv : f2;
            k1 = (nhit == 1) ? key : k1;  f1 = (nhit == 1) ? wv : f1;
            k0 = (nhit == 0) ? key : k0;  f0 = (nhit == 0) ? wv : f0;
            nhit++;
        }
    }

    // ---- Phase 6: hit-chunk merged stores (walk set bits; E[popcount]=1) ----
    {
        float4* Arow4 = (float4*)(A + (size_t)row * NROWS);
        unsigned long long mrem = hitmask;
        while (mrem) {
            int ss = __ffsll((unsigned long long)mrem) - 1;
            mrem &= mrem - 1;
            float4 v = make_float4(0.f, 0.f, 0.f, 0.f);
            #define APPLY_SLOT(kk, ff)                                   \
                if ((int)(kk >> 2) == ss) {                              \
                    int p_ = (int)(kk & 3u);                             \
                    v.x = (p_ == 0) ? ff : v.x;                          \
                    v.y = (p_ == 1) ? ff : v.y;                          \
                    v.z = (p_ == 2) ? ff : v.z;                          \
                    v.w = (p_ == 3) ? ff : v.w;                          \
                }
            APPLY_SLOT(k0, f0)
            APPLY_SLOT(k1, f1)
            APPLY_SLOT(k2, f2)
            APPLY_SLOT(k3, f3)
            #undef APPLY_SLOT
            Arow4[(ss << 5) + j] = v;
        }
    }

    // ---- Phase 7: rare overflow (>4 cols on one lane): ordered dword fixups
    if (nhit > 4) {
        asm volatile("s_waitcnt vmcnt(0)" ::: "memory");
        int cnt = 0;
        for (int jj = 0; jj < 32; ++jj) {
            int c = col_s[r][jj];
            if (((c >> 2) & 31) == j) {
                if (cnt >= 4) {
                    A[(size_t)row * NROWS + c] = w_s[r][jj];
                    asm volatile("s_waitcnt vmcnt(0)" ::: "memory");
                }
                cnt++;
            }
        }
    }

    // ---- Phase 8: embs_hom[row] = sum_j w_j * semH[col_j] (tail of drain) ----
    {
        float2 acc = make_float2(0.f, 0.f);
        const float2* H2 = (const float2*)semH;
        #pragma unroll 4
        for (int jj = 0; jj < KNN; ++jj) {
            float wv = w_s[r][jj];
            int   c  = col_s[r][jj];
            float2 h = H2[(size_t)c * 32 + j];
            acc.x += wv * h.x;
            acc.y += wv * h.y;
        }
        ((float2*)embs)[(size_t)row * 32 + j] = acc;
    }

    // ---- Phase 9: Y passthrough ----
    {
        const float2* Y2 = (const float2*)(Y + (size_t)row0 * DDIM);
        float2* O2 = (float2*)(Yout + (size_t)row0 * DDIM);
        O2[tid] = Y2[tid];
    }
}

extern "C" void kernel_launch(void* const* d_in, const int* in_sizes, int n_in,
                              void* d_out, int out_size, void* d_ws, size_t ws_size,
                              hipStream_t stream) {
    const float* Y      = (const float*)d_in[0];
    const float* semH   = (const float*)d_in[1];
    const float* orthoH = (const float*)d_in[2];
    const int*   idx    = (const int*)d_in[3];
    const void*  alpha  = d_in[4];
    const void*  beta   = d_in[5];

    float* out  = (float*)d_out;
    float* embs = out;                                   // N*D
    float* A    = out + (size_t)NROWS * DDIM;            // N*N
    float* Yout = A + (size_t)NROWS * NROWS;             // N*D

    school_fused_kernel<<<NROWS / 8, 256, 0, stream>>>(
        Y, semH, orthoH, idx, alpha, beta, embs, A, Yout);
}

// Round 9
// 63.367 us; speedup vs baseline: 1.8307x; 1.0929x over previous
//
#include <hip/hip_runtime.h>

#define NROWS 8192
#define DDIM  64
#define KNN   32
#define MAXIT 100

// alpha/beta arrive as 1-element arrays; robust to int32 or float32 encoding.
__device__ __forceinline__ float scalar_val(const void* p) {
    int iv = *(const int*)p;
    if (iv > -1000000 && iv < 1000000) return (float)iv;
    return *(const float*)p;
}

// One block = 8 rows, half-wave (32 lanes) per row.
// R6 structure (best: 63.5us): loads+compute front, embs BEFORE the store
// stream (in-order vmcnt!), then one unconditional merged zero+scatter pass
// over the row (64 float4/lane). This round: 6 waves/EU occupancy for the
// latency-bound front + packed (col,w) LDS to halve DS ops.
__global__ __launch_bounds__(256, 6) void school_fused_kernel(
    const float* __restrict__ Y,
    const float* __restrict__ semH,
    const float* __restrict__ orthoH,
    const int*   __restrict__ idx,
    const void*  alpha_p,
    const void*  beta_p,
    float* __restrict__ embs,   // N*D
    float* __restrict__ A,      // N*N
    float* __restrict__ Yout)   // N*D
{
    __shared__ int    col_s[8][KNN];
    __shared__ float  ad_s[8][KNN];
    __shared__ float2 cw_s[8][KNN];   // packed {bitcast(col), w_deduped}

    const int tid  = threadIdx.x;
    const int j    = tid & 31;      // lane within half-wave = neighbor slot
    const int r    = tid >> 5;      // row-within-block, 0..7 (half-wave id)
    const int row0 = blockIdx.x * 8;
    const int row  = row0 + r;

    const float alpha = scalar_val(alpha_p);
    const float beta  = scalar_val(beta_p);

    // ---- Phase 0: neighbor ids -> LDS ----
    const int col = idx[row * 64 + 1 + j];       // idxa0 = idx[:, 1:33]
    col_s[r][j] = col;

    // ---- Phase 1: distances, cooperative-coalesced (2 cols / 16-lane group)
    const float4* Y4 = (const float4*)Y;
    const float4* O4 = (const float4*)orthoH;
    const int q = j & 15;
    const float4 ownY = Y4[(size_t)row * 16 + q];
    const float4 ownO = O4[(size_t)row * 16 + q];

    #pragma unroll 2
    for (int t = 0; t < 16; ++t) {
        const int c = col_s[r][2 * t + (j >> 4)];
        const float4 gY = Y4[(size_t)c * 16 + q];
        const float4 gO = O4[(size_t)c * 16 + q];
        float ex = ownY.x - gY.x, ey = ownY.y - gY.y,
              ez = ownY.z - gY.z, ew = ownY.w - gY.w;
        float dY = ex * ex + ey * ey + ez * ez + ew * ew;
        ex = ownO.x - gO.x; ey = ownO.y - gO.y;
        ez = ownO.z - gO.z; ew = ownO.w - gO.w;
        float dO = ex * ex + ey * ey + ez * ez + ew * ew;
        #pragma unroll
        for (int mm = 1; mm <= 8; mm <<= 1) {
            dY += __shfl_xor(dY, mm, 64);
            dO += __shfl_xor(dO, mm, 64);
        }
        if ((j & 15) == 0) {
            float dfv = sqrtf(dY + 1e-8f);
            float dxv = sqrtf(dO + 1e-8f);
            ad_s[r][2 * t + (j >> 4)] = -(dxv + beta * dfv) / (2.f * alpha);
        }
    }
    const float ad = ad_s[r][j];

    // ---- Phase 2: simplex projection (32 lanes = one row) ----
    float s = ad;
    #pragma unroll
    for (int mm = 1; mm <= 16; mm <<= 1) s += __shfl_xor(s, mm, 64);
    const float v0 = ad - s * (1.f / 32.f) + (1.f / 32.f);

    // Newton with tolerance exit (full 100 iters like ref if steps stay big).
    float lam = 0.f;
    #pragma unroll 1
    for (int it = 0; it < MAXIT; ++it) {
        float v1 = v0 - lam;
        float p = v1 > 0.f ? v1 : 0.f;
        float c = v1 > 0.f ? 1.f : 0.f;
        #pragma unroll
        for (int mm = 1; mm <= 16; mm <<= 1) {
            p += __shfl_xor(p, mm, 64);
            c += __shfl_xor(c, mm, 64);
        }
        float step = (p - 1.f) / fmaxf(c, 1.f);
        lam += step;
        if (__all(fabsf(step) <= 1e-6f ? 1 : 0)) break;
    }
    const float w = fmaxf(v0 - lam, 0.f);

    // ---- Phase 3: dedupe (np fancy-assignment: last j wins) ----
    bool dead = false;
    for (int jj = j + 1; jj < 32; ++jj)
        dead |= (col_s[r][jj] == col);
    cw_s[r][j] = make_float2(__int_as_float(col), dead ? 0.f : w);

    // ---- Phase 4: embs_hom[row] = sum_j w_j * semH[col_j]  (b64 LDS reads,
    //      gathers issued BEFORE the store stream -> no vmcnt coupling) ----
    {
        float2 acc = make_float2(0.f, 0.f);
        const float2* H2 = (const float2*)semH;
        #pragma unroll 4
        for (int jj = 0; jj < KNN; ++jj) {
            float2 cw = cw_s[r][jj];
            int   c   = __float_as_int(cw.x);
            float wv  = cw.y;
            float2 h = H2[(size_t)c * 32 + j];
            acc.x += wv * h.x;
            acc.y += wv * h.y;
        }
        ((float2*)embs)[(size_t)row * 32 + j] = acc;
    }

    // ---- Phase 5: Y passthrough ----
    {
        const float2* Y2 = (const float2*)(Y + (size_t)row0 * DDIM);
        float2* O2 = (float2*)(Yout + (size_t)row0 * DDIM);
        O2[tid] = Y2[tid];
    }

    // ---- Phase 6: k-slot scan (ascending jj => ascending apply = last-wins)
    // Lane j owns float4 chunks i = 32*ss + j; col c -> owner (c>>2)&31,
    // ss = c>>7, pos = c&3.
    unsigned k0 = 0xFFFFFFFFu, k1 = 0xFFFFFFFFu, k2 = 0xFFFFFFFFu, k3 = 0xFFFFFFFFu;
    float f0 = 0.f, f1 = 0.f, f2 = 0.f, f3 = 0.f;
    int nhit = 0;
    #pragma unroll 1
    for (int jj = 0; jj < 32; ++jj) {
        float2 cw = cw_s[r][jj];
        int c = __float_as_int(cw.x);
        if (((c >> 2) & 31) == j) {
            unsigned key = ((unsigned)(c >> 7) << 2) | (unsigned)(c & 3);
            float wv = cw.y;
            k3 = (nhit == 3) ? key : k3;  f3 = (nhit == 3) ? wv : f3;
            k2 = (nhit == 2) ? key : k2;  f2 = (nhit == 2) ? wv : f2;
            k1 = (nhit == 1) ? key : k1;  f1 = (nhit == 1) ? wv : f1;
            k0 = (nhit == 0) ? key : k0;  f0 = (nhit == 0) ? wv : f0;
            nhit++;
        }
    }

    // ---- Phase 7: merged zero+scatter stream (unconditional 64 float4/lane)
    {
        float4* Arow4 = (float4*)(A + (size_t)row * NROWS);
        #pragma unroll 4
        for (int ss = 0; ss < 64; ++ss) {
            float4 v = make_float4(0.f, 0.f, 0.f, 0.f);
            #define APPLY_SLOT(kk, ff)                                   \
                if ((kk >> 2) == (unsigned)ss) {                         \
                    int p_ = (int)(kk & 3u);                             \
                    v.x = (p_ == 0) ? ff : v.x;                          \
                    v.y = (p_ == 1) ? ff : v.y;                          \
                    v.z = (p_ == 2) ? ff : v.z;                          \
                    v.w = (p_ == 3) ? ff : v.w;                          \
                }
            APPLY_SLOT(k0, f0)
            APPLY_SLOT(k1, f1)
            APPLY_SLOT(k2, f2)
            APPLY_SLOT(k3, f3)
            #undef APPLY_SLOT
            Arow4[(ss << 5) + j] = v;
        }
    }

    // ---- Phase 8: rare overflow (>4 cols on one lane): ordered dword fixups
    if (nhit > 4) {
        asm volatile("s_waitcnt vmcnt(0)" ::: "memory");
        int cnt = 0;
        for (int jj = 0; jj < 32; ++jj) {
            float2 cw = cw_s[r][jj];
            int c = __float_as_int(cw.x);
            if (((c >> 2) & 31) == j) {
                if (cnt >= 4) {
                    A[(size_t)row * NROWS + c] = cw.y;
                    asm volatile("s_waitcnt vmcnt(0)" ::: "memory");
                }
                cnt++;
            }
        }
    }
}

extern "C" void kernel_launch(void* const* d_in, const int* in_sizes, int n_in,
                              void* d_out, int out_size, void* d_ws, size_t ws_size,
                              hipStream_t stream) {
    const float* Y      = (const float*)d_in[0];
    const float* semH   = (const float*)d_in[1];
    const float* orthoH = (const float*)d_in[2];
    const int*   idx    = (const int*)d_in[3];
    const void*  alpha  = d_in[4];
    const void*  beta   = d_in[5];

    float* out  = (float*)d_out;
    float* embs = out;                                   // N*D
    float* A    = out + (size_t)NROWS * DDIM;            // N*N
    float* Yout = A + (size_t)NROWS * NROWS;             // N*D

    school_fused_kernel<<<NROWS / 8, 256, 0, stream>>>(
        Y, semH, orthoH, idx, alpha, beta, embs, A, Yout);
}